// Round 15
// baseline (1580.681 us; speedup 1.0000x reference)
//
#include <hip/hip_runtime.h>

typedef _Float16 f16;
typedef _Float16 f16x8 __attribute__((ext_vector_type(8)));
typedef float f32x16 __attribute__((ext_vector_type(16)));

__device__ __forceinline__ f16x8 cvt8p(const float* p) {
  float4 a = *(const float4*)p;
  float4 b = *(const float4*)(p + 4);
  f16x8 v;
  v[0] = (f16)a.x; v[1] = (f16)a.y; v[2] = (f16)a.z; v[3] = (f16)a.w;
  v[4] = (f16)b.x; v[5] = (f16)b.y; v[6] = (f16)b.z; v[7] = (f16)b.w;
  return v;
}

__device__ __forceinline__ void gload16(const void* g, void* l) {
  __builtin_amdgcn_global_load_lds((const __attribute__((address_space(1))) unsigned int*)g,
                                   (__attribute__((address_space(3))) unsigned int*)l, 16, 0, 0);
}

__device__ __forceinline__ float sigm(float x) {
  return __builtin_amdgcn_rcpf(1.f + __expf(-x));
}
__device__ __forceinline__ float tanh_(float x) {
  x = fminf(15.f, fmaxf(-15.f, x));
  float e = __expf(2.f * x);
  return 1.f - 2.f * __builtin_amdgcn_rcpf(e + 1.f);
}

// ---------------- small utility kernels ----------------

__global__ void k_cvt8(const float* __restrict__ x, f16* __restrict__ y, long n) {
  long i = ((long)blockIdx.x * blockDim.x + threadIdx.x) * 8;
  long stride = (long)gridDim.x * blockDim.x * 8;
  for (; i < n; i += stride) *(f16x8*)(y + i) = cvt8p(x + i);
}

// k_gru v10 weight image, packed in FRAGMENT-LOAD order (coalesced 1KB per
// (chunk,ks,gate) wave-load): [hb 8][chunk 8][ks 4][g 3][lane 64][8 f16].
// Lane l holds B row g*32+(l&31), k elems chunk*64 + ks*16 + (l>>5)*8 .. +7.
// Chunks 0-3 = Wc (K of ag), chunks 4-7 = Whh (K of hin).
__global__ void k_wc3(const float* __restrict__ Wih, const float* __restrict__ W,
                      unsigned char* __restrict__ dstb) {
  int j = blockIdx.x;   // 0..767 = gate*256 + hcol
  int k = threadIdx.x;  // 0..255
  float s = 0.f;
  for (int c = 0; c < 256; ++c) s = fmaf(Wih[j * 256 + c], W[c * 256 + k], s);
  int g = j >> 8, hcol = j & 255;
  int hb = hcol >> 5, trow = hcol & 31;
  int ch = k >> 6, kl = k & 63;
  int ks = kl >> 4, hi2 = (kl >> 3) & 1, el = kl & 7;
  int lane = hi2 * 32 + trow;
  size_t byte = (size_t)hb * 98304 + (size_t)ch * 12288 +
                (size_t)(ks * 3 + g) * 1024 + lane * 16 + el * 2;
  *(f16*)(dstb + byte) = (f16)s;
}

__global__ void k_whh3(const float* __restrict__ Whh, unsigned char* __restrict__ dstb) {
  int j = blockIdx.x;
  int k = threadIdx.x;
  float s = Whh[j * 256 + k];
  int g = j >> 8, hcol = j & 255;
  int hb = hcol >> 5, trow = hcol & 31;
  int ch = 4 + (k >> 6), kl = k & 63;
  int ks = kl >> 4, hi2 = (kl >> 3) & 1, el = kl & 7;
  int lane = hi2 * 32 + trow;
  size_t byte = (size_t)hb * 98304 + (size_t)ch * 12288 +
                (size_t)(ks * 3 + g) * 1024 + lane * 16 + el * 2;
  *(f16*)(dstb + byte) = (f16)s;
}

// k_fn weight image (unchanged): [cg 4][kc 8][R 64][slot 8][8 f16]
__global__ void k_prepw(const float* __restrict__ w, unsigned char* __restrict__ dstb) {
  int j = blockIdx.x;  // output col 0..255
  int cg = j >> 6, R = j & 63;
  for (int k = threadIdx.x; k < 512; k += 256) {
    int kc = k >> 6, kl = k & 63;
    int slot = (kl >> 3) ^ (R & 7);
    size_t byte = (size_t)(cg * 8 + kc) * 8192 + (size_t)R * 128 + slot * 16 + (kl & 7) * 2;
    *(f16*)(dstb + byte) = (f16)w[j * 512 + k];
  }
}

__global__ void k_v(const float* __restrict__ Wih, const float* __restrict__ b,
                    float* __restrict__ v) {
  int j = blockIdx.x * blockDim.x + threadIdx.x;
  if (j < 768) {
    float s = 0.f;
    for (int c = 0; c < 256; ++c) s = fmaf(Wih[j * 256 + c], b[c], s);
    v[j] = s;
  }
}

__global__ void k_hist(const int* __restrict__ dst, int* __restrict__ cnt, int E) {
  int e = blockIdx.x * 256 + threadIdx.x;
  if (e < E) atomicAdd(&cnt[dst[e]], 1);
}

__global__ void k_scan1(const int* __restrict__ deg, int* __restrict__ rowptr,
                        int* __restrict__ bsum, int n) {
  __shared__ int buf[256];
  int i = blockIdx.x * 256 + threadIdx.x;
  int v = (i < n) ? deg[i] : 0;
  buf[threadIdx.x] = v;
  __syncthreads();
  for (int off = 1; off < 256; off <<= 1) {
    int t = 0;
    if ((int)threadIdx.x >= off) t = buf[threadIdx.x - off];
    __syncthreads();
    buf[threadIdx.x] += t;
    __syncthreads();
  }
  if (i < n) rowptr[i] = buf[threadIdx.x] - v;
  if (threadIdx.x == 255) bsum[blockIdx.x] = buf[255];
}

__global__ void k_scan2(int* __restrict__ bsum, int nb) {
  __shared__ int buf[1024];
  int v = ((int)threadIdx.x < nb) ? bsum[threadIdx.x] : 0;
  buf[threadIdx.x] = v;
  __syncthreads();
  for (int off = 1; off < 1024; off <<= 1) {
    int t = 0;
    if ((int)threadIdx.x >= off) t = buf[threadIdx.x - off];
    __syncthreads();
    buf[threadIdx.x] += t;
    __syncthreads();
  }
  if ((int)threadIdx.x < nb) bsum[threadIdx.x] = buf[threadIdx.x] - v;
}

__global__ void k_scan3(int* __restrict__ rowptr, const int* __restrict__ bsum,
                        int n, int E) {
  int i = blockIdx.x * 256 + threadIdx.x;
  if (i < n) rowptr[i] += bsum[blockIdx.x];
  if (i == n) rowptr[n] = E;
}

// fill-by-decrement: consumes the deg counts left by k_hist (cnt -> 0 after),
// so cnt needs only ONE memset for the whole program.
__global__ void k_fill(const int* __restrict__ src, const int* __restrict__ dst,
                       const int* __restrict__ rowptr, int* __restrict__ cnt,
                       int* __restrict__ esrc, int E) {
  int e = blockIdx.x * 256 + threadIdx.x;
  if (e < E) {
    int d = dst[e];
    int r = atomicSub(&cnt[d], 1);  // r in [1..deg]
    esrc[rowptr[d] + r - 1] = src[e];
  }
}

// 2-edge unrolled gather
__global__ void k_gather(const f16* __restrict__ h, const int* __restrict__ rowptr,
                         const int* __restrict__ esrc, f16* __restrict__ ag, int n) {
  int g = threadIdx.x >> 5, l = threadIdx.x & 31;
  int node = blockIdx.x * 8 + g;
  if (node >= n) return;
  int e0 = rowptr[node], e1 = rowptr[node + 1];
  float acc[8];
#pragma unroll
  for (int j = 0; j < 8; ++j) acc[j] = 0.f;
  int e = e0;
  for (; e + 2 <= e1; e += 2) {
    int s0 = esrc[e], s1 = esrc[e + 1];
    f16x8 hv0 = *(const f16x8*)(h + (long)s0 * 256 + l * 8);
    f16x8 hv1 = *(const f16x8*)(h + (long)s1 * 256 + l * 8);
#pragma unroll
    for (int j = 0; j < 8; ++j) acc[j] += (float)hv0[j] + (float)hv1[j];
  }
  if (e < e1) {
    int s0 = esrc[e];
    f16x8 hv0 = *(const f16x8*)(h + (long)s0 * 256 + l * 8);
#pragma unroll
    for (int j = 0; j < 8; ++j) acc[j] += (float)hv0[j];
  }
  f16x8 o;
#pragma unroll
  for (int j = 0; j < 8; ++j) o[j] = (f16)acc[j];
  *(f16x8*)(ag + (long)node * 256 + l * 8) = o;
}

// ---------------- fused GRU kernel v10: streaming-B, no LDS, no K-loop barriers.
// B-fragments read straight from L2 via the repacked image (1KB coalesced per
// wave-load). 256 thr / 4 waves, block = 128 rows x 32 hcols; acc = 4 tiles.
// OOB-row loads unguarded (land in next ws carve; stores guarded).
__global__ __launch_bounds__(256, 4) void k_gru(
    const f16* __restrict__ ag, const f16* __restrict__ hin,
    const unsigned char* __restrict__ wprep, const float* __restrict__ bih,
    const float* __restrict__ bhh, const float* __restrict__ vv,
    const int* __restrict__ rowptr, f16* __restrict__ hout, int n, int nper) {
  __shared__ float Ds[128];
  int bid = blockIdx.x;
  int w = (bid & 7) * nper + (bid >> 3);  // XCD swizzle
  int rt = w >> 3, hb = w & 7;
  int row0 = rt * 128;
  int tid = threadIdx.x, lane = tid & 63, wid = tid >> 6;
  int l31 = lane & 31, hi = lane >> 5;
  const unsigned char* bp = wprep + (size_t)hb * 98304 + lane * 16;

  int arow = row0 + wid * 32 + l31;
  const f16* agp = ag + (size_t)arow * 256 + hi * 8;
  const f16* hp = hin + (size_t)arow * 256 + hi * 8;

  f16x8 a[4];
  auto loadA = [&](const f16* p, int koff) {
#pragma unroll
    for (int ks = 0; ks < 4; ++ks)
      a[ks] = *(const f16x8*)(p + koff + ks * 16);
  };

  f32x16 accR, accZ, accNI, accNH;
#pragma unroll
  for (int j = 0; j < 16; ++j) { accR[j] = 0.f; accZ[j] = 0.f; accNI[j] = 0.f; accNH[j] = 0.f; }

  auto runC = [&](int c, f32x16& aN) {
    const unsigned char* cb = bp + (size_t)c * 12288;
#pragma unroll
    for (int ks = 0; ks < 4; ++ks) {
      f16x8 b0 = *(const f16x8*)(cb + (ks * 3 + 0) * 1024);
      accR = __builtin_amdgcn_mfma_f32_32x32x16_f16(a[ks], b0, accR, 0, 0, 0);
      f16x8 b1 = *(const f16x8*)(cb + (ks * 3 + 1) * 1024);
      accZ = __builtin_amdgcn_mfma_f32_32x32x16_f16(a[ks], b1, accZ, 0, 0, 0);
      f16x8 b2 = *(const f16x8*)(cb + (ks * 3 + 2) * 1024);
      aN = __builtin_amdgcn_mfma_f32_32x32x16_f16(a[ks], b2, aN, 0, 0, 0);
    }
  };

  loadA(agp, 0);
  if (tid < 128) {
    int grow = row0 + tid;
    Ds[tid] = (grow < n) ? (float)(rowptr[grow + 1] - rowptr[grow]) : 0.f;
  }
  __syncthreads();  // Ds ready (only barrier in the kernel)

  runC(0, accNI); loadA(agp, 64);
  runC(1, accNI); loadA(agp, 128);
  runC(2, accNI); loadA(agp, 192);
  runC(3, accNI); loadA(hp, 0);
  runC(4, accNH); loadA(hp, 64);
  runC(5, accNH); loadA(hp, 128);
  runC(6, accNH); loadA(hp, 192);
  runC(7, accNH);

  int gcol = hb * 32 + l31;
  float br = bih[gcol] + bhh[gcol];
  float bz = bih[256 + gcol] + bhh[256 + gcol];
  float bi_n = bih[512 + gcol], bh_n = bhh[512 + gcol];
  float vr = vv[gcol], vz = vv[256 + gcol], vn = vv[512 + gcol];
  int wrow = wid * 32;

#pragma unroll
  for (int rg = 0; rg < 16; ++rg) {
    int crow = (rg & 3) + 8 * (rg >> 2) + 4 * hi;
    int grow = row0 + wrow + crow;
    float dg = Ds[wrow + crow];
    float hold = (float)hin[(size_t)grow * 256 + gcol];
    float r = sigm(accR[rg] + br + dg * vr);
    float z = sigm(accZ[rg] + bz + dg * vz);
    float nn = tanh_(accNI[rg] + bi_n + dg * vn + r * (accNH[rg] + bh_n));
    if (grow < n)
      hout[(size_t)grow * 256 + gcol] = (f16)((1.f - z) * nn + z * hold);
  }
}

// ---------------- fused concat-linear (round-13, frozen): res = [hb16|base16]@w^T+b
template <int WMODE>
__global__ __launch_bounds__(256, 4) void k_fn(
    const f16* __restrict__ hb, const f16* __restrict__ base16,
    const unsigned char* __restrict__ wp, const float* __restrict__ bias,
    float* __restrict__ out32, f16* __restrict__ out16, int n, int nper) {
  __shared__ unsigned char SM[16384];
  int bid = blockIdx.x;
  int w = (bid & 7) * nper + (bid >> 3);
  int rt = w >> 2, cg = w & 3;
  int row0 = rt * 128;
  int tid = threadIdx.x, lane = tid & 63, wid = tid >> 6;
  int l31 = lane & 31, hi = lane >> 5;
  const unsigned char* wb = wp + (size_t)cg * 65536;

  auto stage = [&](int c, unsigned char* dst) {
    const unsigned char* s0 = wb + (size_t)c * 8192;
#pragma unroll
    for (int i = 0; i < 2; ++i) {
      int r = i * 4 + wid;
      gload16(s0 + r * 1024 + lane * 16, dst + r * 1024);
    }
  };

  int arow = row0 + wid * 32 + l31;
  const f16* hbp = hb + (size_t)arow * 256 + hi * 8;
  const f16* bsp = base16 + (size_t)arow * 256 + hi * 8;

  f16x8 a[4];
  auto loadA = [&](const f16* p, int koff) {
#pragma unroll
    for (int ks = 0; ks < 4; ++ks)
      a[ks] = *(const f16x8*)(p + koff + ks * 16);
  };
  int sl0 = l31 & 7;

  f32x16 acc0, acc1;
#pragma unroll
  for (int j = 0; j < 16; ++j) { acc0[j] = 0.f; acc1[j] = 0.f; }

  auto runC = [&](const unsigned char* Bb) {
#pragma unroll
    for (int ks = 0; ks < 4; ++ks) {
      int sl = (ks * 2 + hi) ^ sl0;
      const unsigned char* base = Bb + sl * 16;
      f16x8 b0 = *(const f16x8*)(base + (0 + l31) * 128);
      acc0 = __builtin_amdgcn_mfma_f32_32x32x16_f16(a[ks], b0, acc0, 0, 0, 0);
      f16x8 b1 = *(const f16x8*)(base + (32 + l31) * 128);
      acc1 = __builtin_amdgcn_mfma_f32_32x32x16_f16(a[ks], b1, acc1, 0, 0, 0);
    }
  };

  stage(0, SM);
  loadA(hbp, 0);
  __syncthreads();
  stage(1, SM + 8192); runC(SM);        loadA(hbp, 64);  __syncthreads();
  stage(2, SM);        runC(SM + 8192); loadA(hbp, 128); __syncthreads();
  stage(3, SM + 8192); runC(SM);        loadA(hbp, 192); __syncthreads();
  stage(4, SM);        runC(SM + 8192); loadA(bsp, 0);   __syncthreads();
  stage(5, SM + 8192); runC(SM);        loadA(bsp, 64);  __syncthreads();
  stage(6, SM);        runC(SM + 8192); loadA(bsp, 128); __syncthreads();
  stage(7, SM + 8192); runC(SM);        loadA(bsp, 192); __syncthreads();
  runC(SM + 8192);

  int colb = cg * 64;
  float bb0 = bias[colb + l31], bb1 = bias[colb + 32 + l31];
#pragma unroll
  for (int rg = 0; rg < 16; ++rg) {
    int grow = row0 + wid * 32 + (rg & 3) + 8 * (rg >> 2) + 4 * hi;
    if (grow < n) {
      if (WMODE == 0) {
        out32[(size_t)grow * 256 + colb + l31] = acc0[rg] + bb0;
        out32[(size_t)grow * 256 + colb + 32 + l31] = acc1[rg] + bb1;
      } else {
        out16[(size_t)grow * 256 + colb + l31] = (f16)(acc0[rg] + bb0);
        out16[(size_t)grow * 256 + colb + 32 + l31] = (f16)(acc1[rg] + bb1);
      }
    }
  }
}

// ---------------- launch ----------------
extern "C" void kernel_launch(void* const* d_in, const int* in_sizes, int n_in,
                              void* d_out, int out_size, void* d_ws, size_t ws_size,
                              hipStream_t stream) {
  const float* nodes = (const float*)d_in[0];
  const int* asrc = (const int*)d_in[1];
  const int* adst = (const int*)d_in[2];
  const int* csrc = (const int*)d_in[3];
  const int* cdst = (const int*)d_in[4];
  const float* W_ast = (const float*)d_in[5];
  const float* b_ast = (const float*)d_in[6];
  const float* Wih_a = (const float*)d_in[7];
  const float* Whh_a = (const float*)d_in[8];
  const float* bih_a = (const float*)d_in[9];
  const float* bhh_a = (const float*)d_in[10];
  const float* w1 = (const float*)d_in[11];
  const float* b1 = (const float*)d_in[12];
  const float* W_cpg = (const float*)d_in[13];
  const float* b_cpg = (const float*)d_in[14];
  const float* Wih_c = (const float*)d_in[15];
  const float* Whh_c = (const float*)d_in[16];
  const float* bih_c = (const float*)d_in[17];
  const float* bhh_c = (const float*)d_in[18];
  const float* w2 = (const float*)d_in[19];
  const float* b2 = (const float*)d_in[20];
  float* out = (float*)d_out;

  const int N = in_sizes[0] / 256;  // 150000
  const int EA = in_sizes[1];       // 300000
  const int EC = in_sizes[3];       // 250000
  const long ND = (long)N * 256;

  char* ws = (char*)d_ws;
  size_t off = 0;
  auto carve = [&](size_t bytes) -> char* {
    char* p = ws + off;
    off += (bytes + 255) & ~(size_t)255;
    return p;
  };
  f16* h0 = (f16*)carve(ND * 2);
  f16* h1 = (f16*)carve(ND * 2);
  f16* ag = (f16*)carve(ND * 2);
  f16* nd16 = (f16*)carve(ND * 2);
  unsigned char* wpA = (unsigned char*)carve(786432);  // 8 hb x 8 ch x 12288B
  unsigned char* wpC = (unsigned char*)carve(786432);
  unsigned char* w1p = (unsigned char*)carve(262144);  // 4 cg x 8 kc x 8192B
  unsigned char* w2p = (unsigned char*)carve(262144);
  float* vA = (float*)carve(768 * 4);
  float* vC = (float*)carve(768 * 4);
  int* rowptr = (int*)carve((size_t)(N + 1) * 4);
  int* cnt = (int*)carve((size_t)N * 4);
  int* esrc = (int*)carve((size_t)(EA > EC ? EA : EC) * 4);
  int* bsum = (int*)carve(1024 * 4);
  (void)ws_size; (void)n_in; (void)out_size;

  const int NRB = (N + 127) / 128;   // 1172 row-panels
  const int GGRID = NRB * 8;         // k_gru grid (%8==0)
  const int FGRID = NRB * 4;         // k_fn grid (%8==0)
  const int SBLK = (N + 255) / 256;  // scans
  {
    int blocks = (int)((ND / 8 + 255) / 256);
    if (blocks > 2048) blocks = 2048;
    k_cvt8<<<blocks, 256, 0, stream>>>(nodes, nd16, ND);
  }

  // weight prep
  k_wc3<<<768, 256, 0, stream>>>(Wih_a, W_ast, wpA);
  k_wc3<<<768, 256, 0, stream>>>(Wih_c, W_cpg, wpC);
  k_whh3<<<768, 256, 0, stream>>>(Whh_a, wpA);
  k_whh3<<<768, 256, 0, stream>>>(Whh_c, wpC);
  k_prepw<<<256, 256, 0, stream>>>(w1, w1p);
  k_prepw<<<256, 256, 0, stream>>>(w2, w2p);
  k_v<<<3, 256, 0, stream>>>(Wih_a, b_ast, vA);
  k_v<<<3, 256, 0, stream>>>(Wih_c, b_cpg, vC);
  // single cnt memset for the whole program (k_fill restores cnt to 0)
  hipMemsetAsync(cnt, 0, (size_t)N * 4, stream);

  auto run_branch = [&](const int* src, const int* dst, int E, const unsigned char* wprep,
                        const float* bih, const float* bhh, const float* v,
                        const f16* hstart, f16* t1, f16* t2) {
    k_hist<<<(E + 255) / 256, 256, 0, stream>>>(dst, cnt, E);
    k_scan1<<<SBLK, 256, 0, stream>>>(cnt, rowptr, bsum, N);
    k_scan2<<<1, 1024, 0, stream>>>(bsum, SBLK);
    k_scan3<<<SBLK, 256, 0, stream>>>(rowptr, bsum, N, E);
    k_fill<<<(E + 255) / 256, 256, 0, stream>>>(src, dst, rowptr, cnt, esrc, E);
    k_gather<<<(N + 7) / 8, 256, 0, stream>>>(hstart, rowptr, esrc, ag, N);
    k_gru<<<GGRID, 256, 0, stream>>>(ag, hstart, wprep, bih, bhh, v, rowptr, t1, N, NRB);
    k_gather<<<(N + 7) / 8, 256, 0, stream>>>(t1, rowptr, esrc, ag, N);
    k_gru<<<GGRID, 256, 0, stream>>>(ag, t1, wprep, bih, bhh, v, rowptr, t2, N, NRB);
  };

  // AST branch: nd16 -> h1 -> h0 (h_ast in h0; nd16 = nodes still alive)
  run_branch(asrc, adst, EA, wpA, bih_a, bhh_a, vA, nd16, h1, h0);
  // hiddens (f16) = [h_ast | nodes] @ w1^T + b1 -> h1
  k_fn<1><<<FGRID, 256, 0, stream>>>(h0, nd16, w1p, b1, nullptr, h1, N, FGRID / 8);
  // CPG branch: h1 -> h0 -> nd16 (h_cpg in nd16; h1 = hiddens stays alive)
  run_branch(csrc, cdst, EC, wpC, bih_c, bhh_c, vC, h1, h0, nd16);
  // logits (fp32) = [h_cpg | hiddens] @ w2^T + b2 -> d_out
  k_fn<0><<<FGRID, 256, 0, stream>>>(nd16, h1, w2p, b2, out, nullptr, N, FGRID / 8);
}

// Round 16
// 1414.148 us; speedup vs baseline: 1.1178x; 1.1178x over previous
//
#include <hip/hip_runtime.h>

typedef _Float16 f16;
typedef _Float16 f16x8 __attribute__((ext_vector_type(8)));
typedef float f32x16 __attribute__((ext_vector_type(16)));

__device__ __forceinline__ f16x8 cvt8p(const float* p) {
  float4 a = *(const float4*)p;
  float4 b = *(const float4*)(p + 4);
  f16x8 v;
  v[0] = (f16)a.x; v[1] = (f16)a.y; v[2] = (f16)a.z; v[3] = (f16)a.w;
  v[4] = (f16)b.x; v[5] = (f16)b.y; v[6] = (f16)b.z; v[7] = (f16)b.w;
  return v;
}

__device__ __forceinline__ void gload16(const void* g, void* l) {
  __builtin_amdgcn_global_load_lds((const __attribute__((address_space(1))) unsigned int*)g,
                                   (__attribute__((address_space(3))) unsigned int*)l, 16, 0, 0);
}

__device__ __forceinline__ float sigm(float x) {
  return __builtin_amdgcn_rcpf(1.f + __expf(-x));
}
__device__ __forceinline__ float tanh_(float x) {
  x = fminf(15.f, fmaxf(-15.f, x));
  float e = __expf(2.f * x);
  return 1.f - 2.f * __builtin_amdgcn_rcpf(e + 1.f);
}

// ---------------- small utility kernels ----------------

__global__ void k_cvt8(const float* __restrict__ x, f16* __restrict__ y, long n) {
  long i = ((long)blockIdx.x * blockDim.x + threadIdx.x) * 8;
  long stride = (long)gridDim.x * blockDim.x * 8;
  for (; i < n; i += stride) *(f16x8*)(y + i) = cvt8p(x + i);
}

// k_gru weight image (round-13 layout): [hb 8][kc 8][R 96][slot 8][8 f16]
// hb = hcol>>5; R = gate*32 + trow (trow = hcol&31). kc 0-3: Wc k=kc*64+kl;
// kc 4-7: Whh k=(kc-4)*64+kl. slot = (kl>>3) ^ (trow&7).
__global__ void k_wc2(const float* __restrict__ Wih, const float* __restrict__ W,
                      unsigned char* __restrict__ dstb) {
  int j = blockIdx.x;   // 0..767 = gate*256 + hcol
  int k = threadIdx.x;  // 0..255
  float s = 0.f;
  for (int c = 0; c < 256; ++c) s = fmaf(Wih[j * 256 + c], W[c * 256 + k], s);
  int g = j >> 8, hcol = j & 255;
  int hb = hcol >> 5, trow = hcol & 31;
  int kc = k >> 6, kl = k & 63;
  int slot = (kl >> 3) ^ (trow & 7);
  size_t byte = (size_t)hb * 98304 + (size_t)kc * 12288 +
                (size_t)(g * 32 + trow) * 128 + slot * 16 + (kl & 7) * 2;
  *(f16*)(dstb + byte) = (f16)s;
}

__global__ void k_whh2(const float* __restrict__ Whh, unsigned char* __restrict__ dstb) {
  int j = blockIdx.x;
  int k = threadIdx.x;
  float s = Whh[j * 256 + k];
  int g = j >> 8, hcol = j & 255;
  int hb = hcol >> 5, trow = hcol & 31;
  int kc = 4 + (k >> 6), kl = k & 63;
  int slot = (kl >> 3) ^ (trow & 7);
  size_t byte = (size_t)hb * 98304 + (size_t)kc * 12288 +
                (size_t)(g * 32 + trow) * 128 + slot * 16 + (kl & 7) * 2;
  *(f16*)(dstb + byte) = (f16)s;
}

// k_fn weight image: [cg 4][kc 8][R 64][slot 8][8 f16]
__global__ void k_prepw(const float* __restrict__ w, unsigned char* __restrict__ dstb) {
  int j = blockIdx.x;  // output col 0..255
  int cg = j >> 6, R = j & 63;
  for (int k = threadIdx.x; k < 512; k += 256) {
    int kc = k >> 6, kl = k & 63;
    int slot = (kl >> 3) ^ (R & 7);
    size_t byte = (size_t)(cg * 8 + kc) * 8192 + (size_t)R * 128 + slot * 16 + (kl & 7) * 2;
    *(f16*)(dstb + byte) = (f16)w[j * 512 + k];
  }
}

__global__ void k_v(const float* __restrict__ Wih, const float* __restrict__ b,
                    float* __restrict__ v) {
  int j = blockIdx.x * blockDim.x + threadIdx.x;
  if (j < 768) {
    float s = 0.f;
    for (int c = 0; c < 256; ++c) s = fmaf(Wih[j * 256 + c], b[c], s);
    v[j] = s;
  }
}

__global__ void k_hist(const int* __restrict__ dst, int* __restrict__ cnt, int E) {
  int e = blockIdx.x * 256 + threadIdx.x;
  if (e < E) atomicAdd(&cnt[dst[e]], 1);
}

__global__ void k_scan1(const int* __restrict__ deg, int* __restrict__ rowptr,
                        int* __restrict__ bsum, int n) {
  __shared__ int buf[256];
  int i = blockIdx.x * 256 + threadIdx.x;
  int v = (i < n) ? deg[i] : 0;
  buf[threadIdx.x] = v;
  __syncthreads();
  for (int off = 1; off < 256; off <<= 1) {
    int t = 0;
    if ((int)threadIdx.x >= off) t = buf[threadIdx.x - off];
    __syncthreads();
    buf[threadIdx.x] += t;
    __syncthreads();
  }
  if (i < n) rowptr[i] = buf[threadIdx.x] - v;
  if (threadIdx.x == 255) bsum[blockIdx.x] = buf[255];
}

__global__ void k_scan2(int* __restrict__ bsum, int nb) {
  __shared__ int buf[1024];
  int v = ((int)threadIdx.x < nb) ? bsum[threadIdx.x] : 0;
  buf[threadIdx.x] = v;
  __syncthreads();
  for (int off = 1; off < 1024; off <<= 1) {
    int t = 0;
    if ((int)threadIdx.x >= off) t = buf[threadIdx.x - off];
    __syncthreads();
    buf[threadIdx.x] += t;
    __syncthreads();
  }
  if ((int)threadIdx.x < nb) bsum[threadIdx.x] = buf[threadIdx.x] - v;
}

__global__ void k_scan3(int* __restrict__ rowptr, const int* __restrict__ bsum,
                        int n, int E) {
  int i = blockIdx.x * 256 + threadIdx.x;
  if (i < n) rowptr[i] += bsum[blockIdx.x];
  if (i == n) rowptr[n] = E;
}

// fill-by-decrement: consumes the deg counts left by k_hist (cnt -> 0 after),
// so cnt needs only ONE memset for the whole program.
__global__ void k_fill(const int* __restrict__ src, const int* __restrict__ dst,
                       const int* __restrict__ rowptr, int* __restrict__ cnt,
                       int* __restrict__ esrc, int E) {
  int e = blockIdx.x * 256 + threadIdx.x;
  if (e < E) {
    int d = dst[e];
    int r = atomicSub(&cnt[d], 1);  // r in [1..deg]
    esrc[rowptr[d] + r - 1] = src[e];
  }
}

// 2-edge unrolled gather
__global__ void k_gather(const f16* __restrict__ h, const int* __restrict__ rowptr,
                         const int* __restrict__ esrc, f16* __restrict__ ag, int n) {
  int g = threadIdx.x >> 5, l = threadIdx.x & 31;
  int node = blockIdx.x * 8 + g;
  if (node >= n) return;
  int e0 = rowptr[node], e1 = rowptr[node + 1];
  float acc[8];
#pragma unroll
  for (int j = 0; j < 8; ++j) acc[j] = 0.f;
  int e = e0;
  for (; e + 2 <= e1; e += 2) {
    int s0 = esrc[e], s1 = esrc[e + 1];
    f16x8 hv0 = *(const f16x8*)(h + (long)s0 * 256 + l * 8);
    f16x8 hv1 = *(const f16x8*)(h + (long)s1 * 256 + l * 8);
#pragma unroll
    for (int j = 0; j < 8; ++j) acc[j] += (float)hv0[j] + (float)hv1[j];
  }
  if (e < e1) {
    int s0 = esrc[e];
    f16x8 hv0 = *(const f16x8*)(h + (long)s0 * 256 + l * 8);
#pragma unroll
    for (int j = 0; j < 8; ++j) acc[j] += (float)hv0[j];
  }
  f16x8 o;
#pragma unroll
  for (int j = 0; j < 8; ++j) o[j] = (f16)acc[j];
  *(f16x8*)(ag + (long)node * 256 + l * 8) = o;
}

// ---------------- fused GRU kernel v11: round-13 LDS structure, 256 rows/block.
// 512 thr / 8 waves; each 12KB staged chunk feeds 8 waves (2x amortization vs
// round 13). Double-buffered, 8 barriers; acc = 4 tiles (64 AGPR), ~120 unified
// regs @ lb(512,4) -> 2 blocks/CU. OOB-row loads unguarded (stores guarded).
__global__ __launch_bounds__(512, 4) void k_gru(
    const f16* __restrict__ ag, const f16* __restrict__ hin,
    const unsigned char* __restrict__ wprep, const float* __restrict__ bih,
    const float* __restrict__ bhh, const float* __restrict__ vv,
    const int* __restrict__ rowptr, f16* __restrict__ hout, int n, int nper) {
  __shared__ unsigned char SM[24576 + 1024];
  float* Ds = (float*)(SM + 24576);  // deg[256]
  int bid = blockIdx.x;
  int w = (bid & 7) * nper + (bid >> 3);  // XCD swizzle
  int rt = w >> 3, hb = w & 7;
  int row0 = rt * 256;
  int tid = threadIdx.x, lane = tid & 63, wid = tid >> 6;  // 8 waves
  int l31 = lane & 31, hi = lane >> 5;
  const unsigned char* wb = wprep + (size_t)hb * 98304;

  auto stage = [&](int c, unsigned char* dst) {
    const unsigned char* s0 = wb + (size_t)c * 12288;
    for (int i = wid; i < 12; i += 8)
      gload16(s0 + i * 1024 + lane * 16, dst + i * 1024);
  };

  int arow = row0 + wid * 32 + l31;
  const f16* agp = ag + (size_t)arow * 256 + hi * 8;
  const f16* hp = hin + (size_t)arow * 256 + hi * 8;

  f16x8 a[4];
  auto loadA = [&](const f16* p, int koff) {
#pragma unroll
    for (int ks = 0; ks < 4; ++ks)
      a[ks] = *(const f16x8*)(p + koff + ks * 16);
  };
  int sl0 = l31 & 7;
  auto runC = [&](const unsigned char* Bb, f32x16& aR, f32x16& aZ, f32x16& aN) {
#pragma unroll
    for (int ks = 0; ks < 4; ++ks) {
      int sl = (ks * 2 + hi) ^ sl0;
      const unsigned char* base = Bb + sl * 16;
      f16x8 b0 = *(const f16x8*)(base + (0 * 32 + l31) * 128);
      aR = __builtin_amdgcn_mfma_f32_32x32x16_f16(a[ks], b0, aR, 0, 0, 0);
      f16x8 b1 = *(const f16x8*)(base + (1 * 32 + l31) * 128);
      aZ = __builtin_amdgcn_mfma_f32_32x32x16_f16(a[ks], b1, aZ, 0, 0, 0);
      f16x8 b2 = *(const f16x8*)(base + (2 * 32 + l31) * 128);
      aN = __builtin_amdgcn_mfma_f32_32x32x16_f16(a[ks], b2, aN, 0, 0, 0);
    }
  };

  f32x16 accR, accZ, accNI, accNH;
#pragma unroll
  for (int j = 0; j < 16; ++j) { accR[j] = 0.f; accZ[j] = 0.f; accNI[j] = 0.f; accNH[j] = 0.f; }

  stage(0, SM);
  loadA(agp, 0);
  if (tid < 256) {
    int grow = row0 + tid;
    Ds[tid] = (grow < n) ? (float)(rowptr[grow + 1] - rowptr[grow]) : 0.f;
  }
  __syncthreads();

  stage(1, SM + 12288);
  runC(SM, accR, accZ, accNI);
  loadA(agp, 64);
  __syncthreads();
  stage(2, SM);
  runC(SM + 12288, accR, accZ, accNI);
  loadA(agp, 128);
  __syncthreads();
  stage(3, SM + 12288);
  runC(SM, accR, accZ, accNI);
  loadA(agp, 192);
  __syncthreads();
  stage(4, SM);
  runC(SM + 12288, accR, accZ, accNI);
  loadA(hp, 0);
  __syncthreads();
  stage(5, SM + 12288);
  runC(SM, accR, accZ, accNH);
  loadA(hp, 64);
  __syncthreads();
  stage(6, SM);
  runC(SM + 12288, accR, accZ, accNH);
  loadA(hp, 128);
  __syncthreads();
  stage(7, SM + 12288);
  runC(SM, accR, accZ, accNH);
  loadA(hp, 192);
  __syncthreads();
  runC(SM + 12288, accR, accZ, accNH);

  int gcol = hb * 32 + l31;
  float br = bih[gcol] + bhh[gcol];
  float bz = bih[256 + gcol] + bhh[256 + gcol];
  float bi_n = bih[512 + gcol], bh_n = bhh[512 + gcol];
  float vr = vv[gcol], vz = vv[256 + gcol], vn = vv[512 + gcol];
  int wrow = wid * 32;

#pragma unroll
  for (int rg = 0; rg < 16; ++rg) {
    int crow = (rg & 3) + 8 * (rg >> 2) + 4 * hi;
    int grow = row0 + wrow + crow;
    float dg = Ds[wrow + crow];
    float hold = (float)hin[(size_t)grow * 256 + gcol];
    float r = sigm(accR[rg] + br + dg * vr);
    float z = sigm(accZ[rg] + bz + dg * vz);
    float nn = tanh_(accNI[rg] + bi_n + dg * vn + r * (accNH[rg] + bh_n));
    if (grow < n)
      hout[(size_t)grow * 256 + gcol] = (f16)((1.f - z) * nn + z * hold);
  }
}

// ---------------- fused concat-linear (frozen): res = [hb16|base16]@w^T+b ------
template <int WMODE>
__global__ __launch_bounds__(256, 4) void k_fn(
    const f16* __restrict__ hb, const f16* __restrict__ base16,
    const unsigned char* __restrict__ wp, const float* __restrict__ bias,
    float* __restrict__ out32, f16* __restrict__ out16, int n, int nper) {
  __shared__ unsigned char SM[16384];
  int bid = blockIdx.x;
  int w = (bid & 7) * nper + (bid >> 3);
  int rt = w >> 2, cg = w & 3;
  int row0 = rt * 128;
  int tid = threadIdx.x, lane = tid & 63, wid = tid >> 6;
  int l31 = lane & 31, hi = lane >> 5;
  const unsigned char* wb = wp + (size_t)cg * 65536;

  auto stage = [&](int c, unsigned char* dst) {
    const unsigned char* s0 = wb + (size_t)c * 8192;
#pragma unroll
    for (int i = 0; i < 2; ++i) {
      int r = i * 4 + wid;
      gload16(s0 + r * 1024 + lane * 16, dst + r * 1024);
    }
  };

  int arow = row0 + wid * 32 + l31;
  const f16* hbp = hb + (size_t)arow * 256 + hi * 8;
  const f16* bsp = base16 + (size_t)arow * 256 + hi * 8;

  f16x8 a[4];
  auto loadA = [&](const f16* p, int koff) {
#pragma unroll
    for (int ks = 0; ks < 4; ++ks)
      a[ks] = *(const f16x8*)(p + koff + ks * 16);
  };
  int sl0 = l31 & 7;

  f32x16 acc0, acc1;
#pragma unroll
  for (int j = 0; j < 16; ++j) { acc0[j] = 0.f; acc1[j] = 0.f; }

  auto runC = [&](const unsigned char* Bb) {
#pragma unroll
    for (int ks = 0; ks < 4; ++ks) {
      int sl = (ks * 2 + hi) ^ sl0;
      const unsigned char* base = Bb + sl * 16;
      f16x8 b0 = *(const f16x8*)(base + (0 + l31) * 128);
      acc0 = __builtin_amdgcn_mfma_f32_32x32x16_f16(a[ks], b0, acc0, 0, 0, 0);
      f16x8 b1 = *(const f16x8*)(base + (32 + l31) * 128);
      acc1 = __builtin_amdgcn_mfma_f32_32x32x16_f16(a[ks], b1, acc1, 0, 0, 0);
    }
  };

  stage(0, SM);
  loadA(hbp, 0);
  __syncthreads();
  stage(1, SM + 8192); runC(SM);        loadA(hbp, 64);  __syncthreads();
  stage(2, SM);        runC(SM + 8192); loadA(hbp, 128); __syncthreads();
  stage(3, SM + 8192); runC(SM);        loadA(hbp, 192); __syncthreads();
  stage(4, SM);        runC(SM + 8192); loadA(bsp, 0);   __syncthreads();
  stage(5, SM + 8192); runC(SM);        loadA(bsp, 64);  __syncthreads();
  stage(6, SM);        runC(SM + 8192); loadA(bsp, 128); __syncthreads();
  stage(7, SM + 8192); runC(SM);        loadA(bsp, 192); __syncthreads();
  runC(SM + 8192);

  int colb = cg * 64;
  float bb0 = bias[colb + l31], bb1 = bias[colb + 32 + l31];
#pragma unroll
  for (int rg = 0; rg < 16; ++rg) {
    int grow = row0 + wid * 32 + (rg & 3) + 8 * (rg >> 2) + 4 * hi;
    if (grow < n) {
      if (WMODE == 0) {
        out32[(size_t)grow * 256 + colb + l31] = acc0[rg] + bb0;
        out32[(size_t)grow * 256 + colb + 32 + l31] = acc1[rg] + bb1;
      } else {
        out16[(size_t)grow * 256 + colb + l31] = (f16)(acc0[rg] + bb0);
        out16[(size_t)grow * 256 + colb + 32 + l31] = (f16)(acc1[rg] + bb1);
      }
    }
  }
}

// ---------------- launch ----------------
extern "C" void kernel_launch(void* const* d_in, const int* in_sizes, int n_in,
                              void* d_out, int out_size, void* d_ws, size_t ws_size,
                              hipStream_t stream) {
  const float* nodes = (const float*)d_in[0];
  const int* asrc = (const int*)d_in[1];
  const int* adst = (const int*)d_in[2];
  const int* csrc = (const int*)d_in[3];
  const int* cdst = (const int*)d_in[4];
  const float* W_ast = (const float*)d_in[5];
  const float* b_ast = (const float*)d_in[6];
  const float* Wih_a = (const float*)d_in[7];
  const float* Whh_a = (const float*)d_in[8];
  const float* bih_a = (const float*)d_in[9];
  const float* bhh_a = (const float*)d_in[10];
  const float* w1 = (const float*)d_in[11];
  const float* b1 = (const float*)d_in[12];
  const float* W_cpg = (const float*)d_in[13];
  const float* b_cpg = (const float*)d_in[14];
  const float* Wih_c = (const float*)d_in[15];
  const float* Whh_c = (const float*)d_in[16];
  const float* bih_c = (const float*)d_in[17];
  const float* bhh_c = (const float*)d_in[18];
  const float* w2 = (const float*)d_in[19];
  const float* b2 = (const float*)d_in[20];
  float* out = (float*)d_out;

  const int N = in_sizes[0] / 256;  // 150000
  const int EA = in_sizes[1];       // 300000
  const int EC = in_sizes[3];       // 250000
  const long ND = (long)N * 256;

  char* ws = (char*)d_ws;
  size_t off = 0;
  auto carve = [&](size_t bytes) -> char* {
    char* p = ws + off;
    off += (bytes + 255) & ~(size_t)255;
    return p;
  };
  f16* h0 = (f16*)carve(ND * 2);
  f16* h1 = (f16*)carve(ND * 2);
  f16* ag = (f16*)carve(ND * 2);
  f16* nd16 = (f16*)carve(ND * 2);
  unsigned char* wpA = (unsigned char*)carve(786432);  // 8 hb x 8 kc x 12288B
  unsigned char* wpC = (unsigned char*)carve(786432);
  unsigned char* w1p = (unsigned char*)carve(262144);  // 4 cg x 8 kc x 8192B
  unsigned char* w2p = (unsigned char*)carve(262144);
  float* vA = (float*)carve(768 * 4);
  float* vC = (float*)carve(768 * 4);
  int* rowptr = (int*)carve((size_t)(N + 1) * 4);
  int* cnt = (int*)carve((size_t)N * 4);
  int* esrc = (int*)carve((size_t)(EA > EC ? EA : EC) * 4);
  int* bsum = (int*)carve(1024 * 4);
  (void)ws_size; (void)n_in; (void)out_size;

  const int NR2 = (N + 255) / 256;   // 586 row-panels (256 rows each)
  const int GGRID = NR2 * 8;         // k_gru grid (4688, %8==0)
  const int NRB = (N + 127) / 128;   // 1172
  const int FGRID = NRB * 4;         // k_fn grid (%8==0)
  const int SBLK = (N + 255) / 256;  // scans
  {
    int blocks = (int)((ND / 8 + 255) / 256);
    if (blocks > 2048) blocks = 2048;
    k_cvt8<<<blocks, 256, 0, stream>>>(nodes, nd16, ND);
  }

  // weight prep
  k_wc2<<<768, 256, 0, stream>>>(Wih_a, W_ast, wpA);
  k_wc2<<<768, 256, 0, stream>>>(Wih_c, W_cpg, wpC);
  k_whh2<<<768, 256, 0, stream>>>(Whh_a, wpA);
  k_whh2<<<768, 256, 0, stream>>>(Whh_c, wpC);
  k_prepw<<<256, 256, 0, stream>>>(w1, w1p);
  k_prepw<<<256, 256, 0, stream>>>(w2, w2p);
  k_v<<<3, 256, 0, stream>>>(Wih_a, b_ast, vA);
  k_v<<<3, 256, 0, stream>>>(Wih_c, b_cpg, vC);
  // single cnt memset for the whole program (k_fill restores cnt to 0)
  hipMemsetAsync(cnt, 0, (size_t)N * 4, stream);

  auto run_branch = [&](const int* src, const int* dst, int E, const unsigned char* wprep,
                        const float* bih, const float* bhh, const float* v,
                        const f16* hstart, f16* t1, f16* t2) {
    k_hist<<<(E + 255) / 256, 256, 0, stream>>>(dst, cnt, E);
    k_scan1<<<SBLK, 256, 0, stream>>>(cnt, rowptr, bsum, N);
    k_scan2<<<1, 1024, 0, stream>>>(bsum, SBLK);
    k_scan3<<<SBLK, 256, 0, stream>>>(rowptr, bsum, N, E);
    k_fill<<<(E + 255) / 256, 256, 0, stream>>>(src, dst, rowptr, cnt, esrc, E);
    k_gather<<<(N + 7) / 8, 256, 0, stream>>>(hstart, rowptr, esrc, ag, N);
    k_gru<<<GGRID, 512, 0, stream>>>(ag, hstart, wprep, bih, bhh, v, rowptr, t1, N, NR2);
    k_gather<<<(N + 7) / 8, 256, 0, stream>>>(t1, rowptr, esrc, ag, N);
    k_gru<<<GGRID, 512, 0, stream>>>(ag, t1, wprep, bih, bhh, v, rowptr, t2, N, NR2);
  };

  // AST branch: nd16 -> h1 -> h0 (h_ast in h0; nd16 = nodes still alive)
  run_branch(asrc, adst, EA, wpA, bih_a, bhh_a, vA, nd16, h1, h0);
  // hiddens (f16) = [h_ast | nodes] @ w1^T + b1 -> h1
  k_fn<1><<<FGRID, 256, 0, stream>>>(h0, nd16, w1p, b1, nullptr, h1, N, FGRID / 8);
  // CPG branch: h1 -> h0 -> nd16 (h_cpg in nd16; h1 = hiddens stays alive)
  run_branch(csrc, cdst, EC, wpC, bih_c, bhh_c, vC, h1, h0, nd16);
  // logits (fp32) = [h_cpg | hiddens] @ w2^T + b2 -> d_out
  k_fn<0><<<FGRID, 256, 0, stream>>>(nd16, h1, w2p, b2, out, nullptr, N, FGRID / 8);
}

// Round 17
// 1304.873 us; speedup vs baseline: 1.2114x; 1.0837x over previous
//
#include <hip/hip_runtime.h>

typedef _Float16 f16;
typedef _Float16 f16x8 __attribute__((ext_vector_type(8)));
typedef float f32x16 __attribute__((ext_vector_type(16)));

#define WAITV(N) asm volatile("s_waitcnt vmcnt(" #N ")" ::: "memory")
#define FENCE() __builtin_amdgcn_sched_barrier(0)
#define BARRIER() __builtin_amdgcn_s_barrier()

__device__ __forceinline__ f16x8 cvt8p(const float* p) {
  float4 a = *(const float4*)p;
  float4 b = *(const float4*)(p + 4);
  f16x8 v;
  v[0] = (f16)a.x; v[1] = (f16)a.y; v[2] = (f16)a.z; v[3] = (f16)a.w;
  v[4] = (f16)b.x; v[5] = (f16)b.y; v[6] = (f16)b.z; v[7] = (f16)b.w;
  return v;
}

__device__ __forceinline__ void gload16(const void* g, void* l) {
  __builtin_amdgcn_global_load_lds((const __attribute__((address_space(1))) unsigned int*)g,
                                   (__attribute__((address_space(3))) unsigned int*)l, 16, 0, 0);
}

__device__ __forceinline__ float sigm(float x) {
  return __builtin_amdgcn_rcpf(1.f + __expf(-x));
}
__device__ __forceinline__ float tanh_(float x) {
  x = fminf(15.f, fmaxf(-15.f, x));
  float e = __expf(2.f * x);
  return 1.f - 2.f * __builtin_amdgcn_rcpf(e + 1.f);
}

// ---------------- small utility kernels ----------------

__global__ void k_cvt8(const float* __restrict__ x, f16* __restrict__ y, long n) {
  long i = ((long)blockIdx.x * blockDim.x + threadIdx.x) * 8;
  long stride = (long)gridDim.x * blockDim.x * 8;
  for (; i < n; i += stride) *(f16x8*)(y + i) = cvt8p(x + i);
}

// k_gru weight image (round-13 layout): [hb 8][kc 8][R 96][slot 8][8 f16]
// hb = hcol>>5; R = gate*32 + trow (trow = hcol&31). kc 0-3: Wc k=kc*64+kl;
// kc 4-7: Whh k=(kc-4)*64+kl. slot = (kl>>3) ^ (trow&7).
__global__ void k_wc2(const float* __restrict__ Wih, const float* __restrict__ W,
                      unsigned char* __restrict__ dstb) {
  int j = blockIdx.x;   // 0..767 = gate*256 + hcol
  int k = threadIdx.x;  // 0..255
  float s = 0.f;
  for (int c = 0; c < 256; ++c) s = fmaf(Wih[j * 256 + c], W[c * 256 + k], s);
  int g = j >> 8, hcol = j & 255;
  int hb = hcol >> 5, trow = hcol & 31;
  int kc = k >> 6, kl = k & 63;
  int slot = (kl >> 3) ^ (trow & 7);
  size_t byte = (size_t)hb * 98304 + (size_t)kc * 12288 +
                (size_t)(g * 32 + trow) * 128 + slot * 16 + (kl & 7) * 2;
  *(f16*)(dstb + byte) = (f16)s;
}

__global__ void k_whh2(const float* __restrict__ Whh, unsigned char* __restrict__ dstb) {
  int j = blockIdx.x;
  int k = threadIdx.x;
  float s = Whh[j * 256 + k];
  int g = j >> 8, hcol = j & 255;
  int hb = hcol >> 5, trow = hcol & 31;
  int kc = 4 + (k >> 6), kl = k & 63;
  int slot = (kl >> 3) ^ (trow & 7);
  size_t byte = (size_t)hb * 98304 + (size_t)kc * 12288 +
                (size_t)(g * 32 + trow) * 128 + slot * 16 + (kl & 7) * 2;
  *(f16*)(dstb + byte) = (f16)s;
}

// k_fn weight image: [cg 4][kc 8][R 64][slot 8][8 f16]
__global__ void k_prepw(const float* __restrict__ w, unsigned char* __restrict__ dstb) {
  int j = blockIdx.x;  // output col 0..255
  int cg = j >> 6, R = j & 63;
  for (int k = threadIdx.x; k < 512; k += 256) {
    int kc = k >> 6, kl = k & 63;
    int slot = (kl >> 3) ^ (R & 7);
    size_t byte = (size_t)(cg * 8 + kc) * 8192 + (size_t)R * 128 + slot * 16 + (kl & 7) * 2;
    *(f16*)(dstb + byte) = (f16)w[j * 512 + k];
  }
}

__global__ void k_v(const float* __restrict__ Wih, const float* __restrict__ b,
                    float* __restrict__ v) {
  int j = blockIdx.x * blockDim.x + threadIdx.x;
  if (j < 768) {
    float s = 0.f;
    for (int c = 0; c < 256; ++c) s = fmaf(Wih[j * 256 + c], b[c], s);
    v[j] = s;
  }
}

__global__ void k_hist(const int* __restrict__ dst, int* __restrict__ cnt, int E) {
  int e = blockIdx.x * 256 + threadIdx.x;
  if (e < E) atomicAdd(&cnt[dst[e]], 1);
}

__global__ void k_scan1(const int* __restrict__ deg, int* __restrict__ rowptr,
                        int* __restrict__ bsum, int n) {
  __shared__ int buf[256];
  int i = blockIdx.x * 256 + threadIdx.x;
  int v = (i < n) ? deg[i] : 0;
  buf[threadIdx.x] = v;
  __syncthreads();
  for (int off = 1; off < 256; off <<= 1) {
    int t = 0;
    if ((int)threadIdx.x >= off) t = buf[threadIdx.x - off];
    __syncthreads();
    buf[threadIdx.x] += t;
    __syncthreads();
  }
  if (i < n) rowptr[i] = buf[threadIdx.x] - v;
  if (threadIdx.x == 255) bsum[blockIdx.x] = buf[255];
}

__global__ void k_scan2(int* __restrict__ bsum, int nb) {
  __shared__ int buf[1024];
  int v = ((int)threadIdx.x < nb) ? bsum[threadIdx.x] : 0;
  buf[threadIdx.x] = v;
  __syncthreads();
  for (int off = 1; off < 1024; off <<= 1) {
    int t = 0;
    if ((int)threadIdx.x >= off) t = buf[threadIdx.x - off];
    __syncthreads();
    buf[threadIdx.x] += t;
    __syncthreads();
  }
  if ((int)threadIdx.x < nb) bsum[threadIdx.x] = buf[threadIdx.x] - v;
}

__global__ void k_scan3(int* __restrict__ rowptr, const int* __restrict__ bsum,
                        int n, int E) {
  int i = blockIdx.x * 256 + threadIdx.x;
  if (i < n) rowptr[i] += bsum[blockIdx.x];
  if (i == n) rowptr[n] = E;
}

// fill-by-decrement: consumes the deg counts left by k_hist (cnt -> 0 after),
// so cnt needs only ONE memset for the whole program.
__global__ void k_fill(const int* __restrict__ src, const int* __restrict__ dst,
                       const int* __restrict__ rowptr, int* __restrict__ cnt,
                       int* __restrict__ esrc, int E) {
  int e = blockIdx.x * 256 + threadIdx.x;
  if (e < E) {
    int d = dst[e];
    int r = atomicSub(&cnt[d], 1);  // r in [1..deg]
    esrc[rowptr[d] + r - 1] = src[e];
  }
}

// 2-edge unrolled gather
__global__ void k_gather(const f16* __restrict__ h, const int* __restrict__ rowptr,
                         const int* __restrict__ esrc, f16* __restrict__ ag, int n) {
  int g = threadIdx.x >> 5, l = threadIdx.x & 31;
  int node = blockIdx.x * 8 + g;
  if (node >= n) return;
  int e0 = rowptr[node], e1 = rowptr[node + 1];
  float acc[8];
#pragma unroll
  for (int j = 0; j < 8; ++j) acc[j] = 0.f;
  int e = e0;
  for (; e + 2 <= e1; e += 2) {
    int s0 = esrc[e], s1 = esrc[e + 1];
    f16x8 hv0 = *(const f16x8*)(h + (long)s0 * 256 + l * 8);
    f16x8 hv1 = *(const f16x8*)(h + (long)s1 * 256 + l * 8);
#pragma unroll
    for (int j = 0; j < 8; ++j) acc[j] += (float)hv0[j] + (float)hv1[j];
  }
  if (e < e1) {
    int s0 = esrc[e];
    f16x8 hv0 = *(const f16x8*)(h + (long)s0 * 256 + l * 8);
#pragma unroll
    for (int j = 0; j < 8; ++j) acc[j] += (float)hv0[j];
  }
  f16x8 o;
#pragma unroll
  for (int j = 0; j < 8; ++j) o[j] = (f16)acc[j];
  *(f16x8*)(ag + (long)node * 256 + l * 8) = o;
}

// ---------------- fused GRU kernel v12: round-13 geometry (128 rows, 4 waves) +
// counted-vmcnt 3-buffer pipeline. Stage prefetch depth 2, A ping-pong a0/a1.
// Raw s_barrier + s_waitcnt vmcnt(N) (N derived: 11 steady, 8 tail) — loads stay
// in flight across barriers. Correctness: per-wave vmcnt + barrier rendezvous
// => cross-wave DMA visibility; buffers recycled 3 chunks after last read.
// OOB-row loads unguarded (stores guarded).
__global__ __launch_bounds__(256, 3) void k_gru(
    const f16* __restrict__ ag, const f16* __restrict__ hin,
    const unsigned char* __restrict__ wprep, const float* __restrict__ bih,
    const float* __restrict__ bhh, const float* __restrict__ vv,
    const int* __restrict__ rowptr, f16* __restrict__ hout, int n, int nper) {
  __shared__ unsigned char SM[3 * 12288 + 512];
  float* Ds = (float*)(SM + 36864);  // deg[128]
  int bid = blockIdx.x;
  int w = (bid & 7) * nper + (bid >> 3);  // XCD swizzle
  int rt = w >> 3, hb = w & 7;
  int row0 = rt * 128;
  int tid = threadIdx.x, lane = tid & 63, wid = tid >> 6;  // 4 waves
  int l31 = lane & 31, hi = lane >> 5;
  const unsigned char* wb = wprep + (size_t)hb * 98304;

  auto stage = [&](int c, int bufi) {
    const unsigned char* s0 = wb + (size_t)c * 12288;
    unsigned char* dst = SM + (size_t)bufi * 12288;
#pragma unroll
    for (int i = 0; i < 3; ++i) {
      int r = i * 4 + wid;
      gload16(s0 + r * 1024 + lane * 16, dst + r * 1024);
    }
  };

  int arow = row0 + wid * 32 + l31;
  const f16* agp = ag + (size_t)arow * 256 + hi * 8;
  const f16* hp = hin + (size_t)arow * 256 + hi * 8;

  f16x8 a0[4], a1[4];
  auto loadAInto = [&](f16x8(&a)[4], const f16* p, int koff) {
#pragma unroll
    for (int ks = 0; ks < 4; ++ks)
      a[ks] = *(const f16x8*)(p + koff + ks * 16);
  };
  int sl0 = l31 & 7;
  auto runC = [&](const f16x8(&a)[4], const unsigned char* Bb,
                  f32x16& aR, f32x16& aZ, f32x16& aN) {
#pragma unroll
    for (int ks = 0; ks < 4; ++ks) {
      int sl = (ks * 2 + hi) ^ sl0;
      const unsigned char* base = Bb + sl * 16;
      f16x8 b0 = *(const f16x8*)(base + (0 * 32 + l31) * 128);
      aR = __builtin_amdgcn_mfma_f32_32x32x16_f16(a[ks], b0, aR, 0, 0, 0);
      f16x8 b1 = *(const f16x8*)(base + (1 * 32 + l31) * 128);
      aZ = __builtin_amdgcn_mfma_f32_32x32x16_f16(a[ks], b1, aZ, 0, 0, 0);
      f16x8 b2 = *(const f16x8*)(base + (2 * 32 + l31) * 128);
      aN = __builtin_amdgcn_mfma_f32_32x32x16_f16(a[ks], b2, aN, 0, 0, 0);
    }
  };

  f32x16 accR, accZ, accNI, accNH;
#pragma unroll
  for (int j = 0; j < 16; ++j) { accR[j] = 0.f; accZ[j] = 0.f; accNI[j] = 0.f; accNH[j] = 0.f; }

  // prologue: prefetch chunks 0,1 + A(c0) + Ds; one full drain
  stage(0, 0);
  stage(1, 1);
  loadAInto(a0, agp, 0);
  if (tid < 128) {
    int grow = row0 + tid;
    Ds[tid] = (grow < n) ? (float)(rowptr[grow + 1] - rowptr[grow]) : 0.f;
  }
  __syncthreads();

  // c=0: B0
  stage(2, 2);
  runC(a0, SM, accR, accZ, accNI);
  loadAInto(a1, agp, 64);
  FENCE(); BARRIER(); FENCE();
  // c=1: B1
  stage(3, 0);
  runC(a1, SM + 12288, accR, accZ, accNI);
  loadAInto(a0, agp, 128);
  WAITV(11); FENCE(); BARRIER(); FENCE();
  // c=2: B2
  stage(4, 1);
  runC(a0, SM + 24576, accR, accZ, accNI);
  loadAInto(a1, agp, 192);
  WAITV(11); FENCE(); BARRIER(); FENCE();
  // c=3: B0
  stage(5, 2);
  runC(a1, SM, accR, accZ, accNI);
  loadAInto(a0, hp, 0);
  WAITV(11); FENCE(); BARRIER(); FENCE();
  // c=4: B1
  stage(6, 0);
  runC(a0, SM + 12288, accR, accZ, accNH);
  loadAInto(a1, hp, 64);
  WAITV(11); FENCE(); BARRIER(); FENCE();
  // c=5: B2
  stage(7, 1);
  runC(a1, SM + 24576, accR, accZ, accNH);
  loadAInto(a0, hp, 128);
  WAITV(11); FENCE(); BARRIER(); FENCE();
  // c=6: B0
  runC(a0, SM, accR, accZ, accNH);
  loadAInto(a1, hp, 192);
  WAITV(8); FENCE(); BARRIER(); FENCE();
  // c=7: B1
  runC(a1, SM + 12288, accR, accZ, accNH);

  int gcol = hb * 32 + l31;
  float br = bih[gcol] + bhh[gcol];
  float bz = bih[256 + gcol] + bhh[256 + gcol];
  float bi_n = bih[512 + gcol], bh_n = bhh[512 + gcol];
  float vr = vv[gcol], vz = vv[256 + gcol], vn = vv[512 + gcol];
  int wrow = wid * 32;

#pragma unroll
  for (int rg = 0; rg < 16; ++rg) {
    int crow = (rg & 3) + 8 * (rg >> 2) + 4 * hi;
    int grow = row0 + wrow + crow;
    float dg = Ds[wrow + crow];
    float hold = (float)hin[(size_t)grow * 256 + gcol];
    float r = sigm(accR[rg] + br + dg * vr);
    float z = sigm(accZ[rg] + bz + dg * vz);
    float nn = tanh_(accNI[rg] + bi_n + dg * vn + r * (accNH[rg] + bh_n));
    if (grow < n)
      hout[(size_t)grow * 256 + gcol] = (f16)((1.f - z) * nn + z * hold);
  }
}

// ---------------- fused concat-linear (frozen): res = [hb16|base16]@w^T+b ------
template <int WMODE>
__global__ __launch_bounds__(256, 4) void k_fn(
    const f16* __restrict__ hb, const f16* __restrict__ base16,
    const unsigned char* __restrict__ wp, const float* __restrict__ bias,
    float* __restrict__ out32, f16* __restrict__ out16, int n, int nper) {
  __shared__ unsigned char SM[16384];
  int bid = blockIdx.x;
  int w = (bid & 7) * nper + (bid >> 3);
  int rt = w >> 2, cg = w & 3;
  int row0 = rt * 128;
  int tid = threadIdx.x, lane = tid & 63, wid = tid >> 6;
  int l31 = lane & 31, hi = lane >> 5;
  const unsigned char* wb = wp + (size_t)cg * 65536;

  auto stage = [&](int c, unsigned char* dst) {
    const unsigned char* s0 = wb + (size_t)c * 8192;
#pragma unroll
    for (int i = 0; i < 2; ++i) {
      int r = i * 4 + wid;
      gload16(s0 + r * 1024 + lane * 16, dst + r * 1024);
    }
  };

  int arow = row0 + wid * 32 + l31;
  const f16* hbp = hb + (size_t)arow * 256 + hi * 8;
  const f16* bsp = base16 + (size_t)arow * 256 + hi * 8;

  f16x8 a[4];
  auto loadA = [&](const f16* p, int koff) {
#pragma unroll
    for (int ks = 0; ks < 4; ++ks)
      a[ks] = *(const f16x8*)(p + koff + ks * 16);
  };
  int sl0 = l31 & 7;

  f32x16 acc0, acc1;
#pragma unroll
  for (int j = 0; j < 16; ++j) { acc0[j] = 0.f; acc1[j] = 0.f; }

  auto runC = [&](const unsigned char* Bb) {
#pragma unroll
    for (int ks = 0; ks < 4; ++ks) {
      int sl = (ks * 2 + hi) ^ sl0;
      const unsigned char* base = Bb + sl * 16;
      f16x8 b0 = *(const f16x8*)(base + (0 + l31) * 128);
      acc0 = __builtin_amdgcn_mfma_f32_32x32x16_f16(a[ks], b0, acc0, 0, 0, 0);
      f16x8 b1 = *(const f16x8*)(base + (32 + l31) * 128);
      acc1 = __builtin_amdgcn_mfma_f32_32x32x16_f16(a[ks], b1, acc1, 0, 0, 0);
    }
  };

  stage(0, SM);
  loadA(hbp, 0);
  __syncthreads();
  stage(1, SM + 8192); runC(SM);        loadA(hbp, 64);  __syncthreads();
  stage(2, SM);        runC(SM + 8192); loadA(hbp, 128); __syncthreads();
  stage(3, SM + 8192); runC(SM);        loadA(hbp, 192); __syncthreads();
  stage(4, SM);        runC(SM + 8192); loadA(bsp, 0);   __syncthreads();
  stage(5, SM + 8192); runC(SM);        loadA(bsp, 64);  __syncthreads();
  stage(6, SM);        runC(SM + 8192); loadA(bsp, 128); __syncthreads();
  stage(7, SM + 8192); runC(SM);        loadA(bsp, 192); __syncthreads();
  runC(SM + 8192);

  int colb = cg * 64;
  float bb0 = bias[colb + l31], bb1 = bias[colb + 32 + l31];
#pragma unroll
  for (int rg = 0; rg < 16; ++rg) {
    int grow = row0 + wid * 32 + (rg & 3) + 8 * (rg >> 2) + 4 * hi;
    if (grow < n) {
      if (WMODE == 0) {
        out32[(size_t)grow * 256 + colb + l31] = acc0[rg] + bb0;
        out32[(size_t)grow * 256 + colb + 32 + l31] = acc1[rg] + bb1;
      } else {
        out16[(size_t)grow * 256 + colb + l31] = (f16)(acc0[rg] + bb0);
        out16[(size_t)grow * 256 + colb + 32 + l31] = (f16)(acc1[rg] + bb1);
      }
    }
  }
}

// ---------------- launch ----------------
extern "C" void kernel_launch(void* const* d_in, const int* in_sizes, int n_in,
                              void* d_out, int out_size, void* d_ws, size_t ws_size,
                              hipStream_t stream) {
  const float* nodes = (const float*)d_in[0];
  const int* asrc = (const int*)d_in[1];
  const int* adst = (const int*)d_in[2];
  const int* csrc = (const int*)d_in[3];
  const int* cdst = (const int*)d_in[4];
  const float* W_ast = (const float*)d_in[5];
  const float* b_ast = (const float*)d_in[6];
  const float* Wih_a = (const float*)d_in[7];
  const float* Whh_a = (const float*)d_in[8];
  const float* bih_a = (const float*)d_in[9];
  const float* bhh_a = (const float*)d_in[10];
  const float* w1 = (const float*)d_in[11];
  const float* b1 = (const float*)d_in[12];
  const float* W_cpg = (const float*)d_in[13];
  const float* b_cpg = (const float*)d_in[14];
  const float* Wih_c = (const float*)d_in[15];
  const float* Whh_c = (const float*)d_in[16];
  const float* bih_c = (const float*)d_in[17];
  const float* bhh_c = (const float*)d_in[18];
  const float* w2 = (const float*)d_in[19];
  const float* b2 = (const float*)d_in[20];
  float* out = (float*)d_out;

  const int N = in_sizes[0] / 256;  // 150000
  const int EA = in_sizes[1];       // 300000
  const int EC = in_sizes[3];       // 250000
  const long ND = (long)N * 256;

  char* ws = (char*)d_ws;
  size_t off = 0;
  auto carve = [&](size_t bytes) -> char* {
    char* p = ws + off;
    off += (bytes + 255) & ~(size_t)255;
    return p;
  };
  f16* h0 = (f16*)carve(ND * 2);
  f16* h1 = (f16*)carve(ND * 2);
  f16* ag = (f16*)carve(ND * 2);
  f16* nd16 = (f16*)carve(ND * 2);
  unsigned char* wpA = (unsigned char*)carve(786432);  // 8 hb x 8 kc x 12288B
  unsigned char* wpC = (unsigned char*)carve(786432);
  unsigned char* w1p = (unsigned char*)carve(262144);  // 4 cg x 8 kc x 8192B
  unsigned char* w2p = (unsigned char*)carve(262144);
  float* vA = (float*)carve(768 * 4);
  float* vC = (float*)carve(768 * 4);
  int* rowptr = (int*)carve((size_t)(N + 1) * 4);
  int* cnt = (int*)carve((size_t)N * 4);
  int* esrc = (int*)carve((size_t)(EA > EC ? EA : EC) * 4);
  int* bsum = (int*)carve(1024 * 4);
  (void)ws_size; (void)n_in; (void)out_size;

  const int NRB = (N + 127) / 128;   // 1172 row-panels (128 rows)
  const int GGRID = NRB * 8;         // k_gru grid (%8==0)
  const int FGRID = NRB * 4;         // k_fn grid (%8==0)
  const int SBLK = (N + 255) / 256;  // scans
  {
    int blocks = (int)((ND / 8 + 255) / 256);
    if (blocks > 2048) blocks = 2048;
    k_cvt8<<<blocks, 256, 0, stream>>>(nodes, nd16, ND);
  }

  // weight prep
  k_wc2<<<768, 256, 0, stream>>>(Wih_a, W_ast, wpA);
  k_wc2<<<768, 256, 0, stream>>>(Wih_c, W_cpg, wpC);
  k_whh2<<<768, 256, 0, stream>>>(Whh_a, wpA);
  k_whh2<<<768, 256, 0, stream>>>(Whh_c, wpC);
  k_prepw<<<256, 256, 0, stream>>>(w1, w1p);
  k_prepw<<<256, 256, 0, stream>>>(w2, w2p);
  k_v<<<3, 256, 0, stream>>>(Wih_a, b_ast, vA);
  k_v<<<3, 256, 0, stream>>>(Wih_c, b_cpg, vC);
  // single cnt memset for the whole program (k_fill restores cnt to 0)
  hipMemsetAsync(cnt, 0, (size_t)N * 4, stream);

  auto run_branch = [&](const int* src, const int* dst, int E, const unsigned char* wprep,
                        const float* bih, const float* bhh, const float* v,
                        const f16* hstart, f16* t1, f16* t2) {
    k_hist<<<(E + 255) / 256, 256, 0, stream>>>(dst, cnt, E);
    k_scan1<<<SBLK, 256, 0, stream>>>(cnt, rowptr, bsum, N);
    k_scan2<<<1, 1024, 0, stream>>>(bsum, SBLK);
    k_scan3<<<SBLK, 256, 0, stream>>>(rowptr, bsum, N, E);
    k_fill<<<(E + 255) / 256, 256, 0, stream>>>(src, dst, rowptr, cnt, esrc, E);
    k_gather<<<(N + 7) / 8, 256, 0, stream>>>(hstart, rowptr, esrc, ag, N);
    k_gru<<<GGRID, 256, 0, stream>>>(ag, hstart, wprep, bih, bhh, v, rowptr, t1, N, NRB);
    k_gather<<<(N + 7) / 8, 256, 0, stream>>>(t1, rowptr, esrc, ag, N);
    k_gru<<<GGRID, 256, 0, stream>>>(ag, t1, wprep, bih, bhh, v, rowptr, t2, N, NRB);
  };

  // AST branch: nd16 -> h1 -> h0 (h_ast in h0; nd16 = nodes still alive)
  run_branch(asrc, adst, EA, wpA, bih_a, bhh_a, vA, nd16, h1, h0);
  // hiddens (f16) = [h_ast | nodes] @ w1^T + b1 -> h1
  k_fn<1><<<FGRID, 256, 0, stream>>>(h0, nd16, w1p, b1, nullptr, h1, N, FGRID / 8);
  // CPG branch: h1 -> h0 -> nd16 (h_cpg in nd16; h1 = hiddens stays alive)
  run_branch(csrc, cdst, EC, wpC, bih_c, bhh_c, vC, h1, h0, nd16);
  // logits (fp32) = [h_cpg | hiddens] @ w2^T + b2 -> d_out
  k_fn<0><<<FGRID, 256, 0, stream>>>(nd16, h1, w2p, b2, out, nullptr, N, FGRID / 8);
}